// Round 1
// 658.237 us; speedup vs baseline: 1.2245x; 1.2245x over previous
//
#include <hip/hip_runtime.h>

#define N_NODES 50000
#define N_EDGES 1600000
#define IN_CH   256
#define ADP     64
#define EDGE_DIM 32
#define NB_SCAN 196   // ceil(50000/256) == number of 256-node groups
#define GRP     196
#define GCAP    12288 // per-group bucket capacity (mean 8192, sd ~90 -> 45 sigma)
#define EPB_A   8192  // edges per block in k_bucket

typedef __fp16 h2 __attribute__((ext_vector_type(2)));
union UH { unsigned int u; h2 h; };

// ---------------- K_A: coarse bucket by 256-node group -----------------------
// Block-aggregated reservations: LDS count -> one global atomicAdd per group
// per block -> append into contiguous per-block slab. Writes stay line-local.
__global__ __launch_bounds__(256) void k_bucket(const int* __restrict__ ei_src,
                                                int* __restrict__ gcnt,
                                                int* __restrict__ gbuf) {
    __shared__ int cnt[GRP];
    __shared__ int cur[GRP];
    int t = threadIdx.x;
    if (t < GRP) cnt[t] = 0;
    __syncthreads();
    int base = blockIdx.x * EPB_A;
    int s[32];
    #pragma unroll
    for (int k = 0; k < 32; k++) {
        int e = base + k * 256 + t;
        int v = (e < N_EDGES) ? ei_src[e] : -1;
        s[k] = v;
        if (v >= 0) atomicAdd(&cnt[v >> 8], 1);
    }
    __syncthreads();
    if (t < GRP) cur[t] = atomicAdd(&gcnt[t], cnt[t]);
    __syncthreads();
    #pragma unroll
    for (int k = 0; k < 32; k++) {
        int v = s[k];
        if (v >= 0) {
            int e = base + k * 256 + t;
            int g = v >> 8;
            int slot = atomicAdd(&cur[g], 1);
            if (slot < GCAP)
                gbuf[g * GCAP + slot] = (e << 8) | (v & 255);
        }
    }
}

// ---------------- K_scan: scan the 196 group counts (1 block) ----------------
__global__ __launch_bounds__(256) void k_bscan(const int* __restrict__ bsum,
                                               int* __restrict__ bpre) {
    __shared__ int a[256], b[256];
    int t = threadIdx.x;
    int v = (t < NB_SCAN) ? bsum[t] : 0;
    a[t] = v; __syncthreads();
    int* src = a; int* dst = b;
    for (int o = 1; o < 256; o <<= 1) {
        int x = src[t]; if (t >= o) x += src[t - o];
        dst[t] = x; __syncthreads();
        int* tmp = src; src = dst; dst = tmp;
    }
    if (t < NB_SCAN) bpre[t] = src[t] - v;
}

// ---------------- K_B: per-group deg/offs/elist build ------------------------
// One block per group. Degree count + prefix scan in LDS; elist writes land in
// the group's contiguous ~33KB region, owned by this CU -> full lines, once.
__global__ __launch_bounds__(256) void k_build(const int* __restrict__ gcnt,
                                               const int* __restrict__ gbase,
                                               const int* __restrict__ gbuf,
                                               int* __restrict__ deg,
                                               int* __restrict__ offs,
                                               int* __restrict__ elist) {
    __shared__ int dcnt[256];
    __shared__ int a[256], b[256];
    __shared__ int cur[256];
    int t = threadIdx.x;
    int g = blockIdx.x;
    int sz = gcnt[g];
    if (sz > GCAP) sz = GCAP;
    int base = gbase[g];
    const int* src = gbuf + (size_t)g * GCAP;
    dcnt[t] = 0;
    __syncthreads();
    for (int i = t; i < sz; i += 256)
        atomicAdd(&dcnt[src[i] & 255], 1);
    __syncthreads();
    int v = dcnt[t];
    a[t] = v; __syncthreads();
    int* sp = a; int* dp = b;
    for (int o = 1; o < 256; o <<= 1) {
        int x = sp[t]; if (t >= o) x += sp[t - o];
        dp[t] = x; __syncthreads();
        int* tmp = sp; sp = dp; dp = tmp;
    }
    int pref = sp[t] - v;   // exclusive within group
    int n = g * 256 + t;
    if (n < N_NODES) { deg[n] = v; offs[n] = base + pref; }
    cur[t] = pref;
    __syncthreads();
    for (int i = t; i < sz; i += 256) {
        int p = src[i];
        int slot = atomicAdd(&cur[p & 255], 1);
        elist[base + slot] = p >> 8;
    }
}

// ---------------- K3: gather + time-proj (f16 dot2) + mean -------------------
// One wave per node. Stage 8 edges/chunk: coalesced float4 gather -> cvt to
// f16 -> 8B LDS write per lane (row = 64B). Per edge: 4 ds_read_b128 +
// 16 v_dot2_f32_f16 (4 chains).
__global__ __launch_bounds__(256) void k_gatherproj(const float* __restrict__ ea,
                                                    const int* __restrict__ offs,
                                                    const int* __restrict__ deg,
                                                    const int* __restrict__ elist,
                                                    const float* __restrict__ Wt,
                                                    const float* __restrict__ bt,
                                                    float* __restrict__ ntf) {
    __shared__ unsigned long long buf[4][8][8];   // [wave][edge][8B seg] = 2KB
    int t = threadIdx.x;
    int lane = t & 63, wv = t >> 6;
    h2 wh[16];
    {
        const float4* w4 = (const float4*)(Wt + (size_t)lane * EDGE_DIM);
        #pragma unroll
        for (int k4 = 0; k4 < 8; k4++) {
            float4 v = w4[k4];
            wh[2 * k4 + 0] = __builtin_amdgcn_cvt_pkrtz(v.x, v.y);
            wh[2 * k4 + 1] = __builtin_amdgcn_cvt_pkrtz(v.z, v.w);
        }
    }
    float bias = bt[lane];
    int n = blockIdx.x * 4 + wv;
    if (n >= N_NODES) return;
    int st = offs[n], d = deg[n];
    int sub = lane >> 3;   // edge slot 0..7
    int seg = lane & 7;    // 16B (4-float) segment within row
    const float4* ea4 = (const float4*)ea;
    float acc = 0.f;
    for (int base = 0; base < d; base += 8) {
        int cnt = min(8, d - base);
        int e = elist[st + base + min(sub, cnt - 1)];
        float4 v = ea4[(size_t)e * 8 + seg];
        UH lo, hi;
        lo.h = __builtin_amdgcn_cvt_pkrtz(v.x, v.y);
        hi.h = __builtin_amdgcn_cvt_pkrtz(v.z, v.w);
        buf[wv][sub][seg] = ((unsigned long long)hi.u << 32) | lo.u;
        const uint4* bb = (const uint4*)&buf[wv][0][0];
        #pragma unroll 1
        for (int j = 0; j < cnt; j++) {
            uint4 q0 = bb[j * 4 + 0];
            uint4 q1 = bb[j * 4 + 1];
            uint4 q2 = bb[j * 4 + 2];
            uint4 q3 = bb[j * 4 + 3];
            UH c;
            float s0 = bias, s1 = 0.f, s2 = 0.f, s3 = 0.f;
            c.u = q0.x; s0 = __builtin_amdgcn_fdot2(c.h, wh[ 0], s0, false);
            c.u = q0.y; s1 = __builtin_amdgcn_fdot2(c.h, wh[ 1], s1, false);
            c.u = q0.z; s2 = __builtin_amdgcn_fdot2(c.h, wh[ 2], s2, false);
            c.u = q0.w; s3 = __builtin_amdgcn_fdot2(c.h, wh[ 3], s3, false);
            c.u = q1.x; s0 = __builtin_amdgcn_fdot2(c.h, wh[ 4], s0, false);
            c.u = q1.y; s1 = __builtin_amdgcn_fdot2(c.h, wh[ 5], s1, false);
            c.u = q1.z; s2 = __builtin_amdgcn_fdot2(c.h, wh[ 6], s2, false);
            c.u = q1.w; s3 = __builtin_amdgcn_fdot2(c.h, wh[ 7], s3, false);
            c.u = q2.x; s0 = __builtin_amdgcn_fdot2(c.h, wh[ 8], s0, false);
            c.u = q2.y; s1 = __builtin_amdgcn_fdot2(c.h, wh[ 9], s1, false);
            c.u = q2.z; s2 = __builtin_amdgcn_fdot2(c.h, wh[10], s2, false);
            c.u = q2.w; s3 = __builtin_amdgcn_fdot2(c.h, wh[11], s3, false);
            c.u = q3.x; s0 = __builtin_amdgcn_fdot2(c.h, wh[12], s0, false);
            c.u = q3.y; s1 = __builtin_amdgcn_fdot2(c.h, wh[13], s1, false);
            c.u = q3.z; s2 = __builtin_amdgcn_fdot2(c.h, wh[14], s2, false);
            c.u = q3.w; s3 = __builtin_amdgcn_fdot2(c.h, wh[15], s3, false);
            acc += fmaxf((s0 + s1) + (s2 + s3), 0.f);
        }
    }
    ntf[(size_t)n * ADP + lane] = acc / fmaxf((float)d, 1.f);
}

// ---------------- K4: node_feat = relu(x @ W_down^T + b_down) ----------------
__global__ __launch_bounds__(256) void k_down(const float* __restrict__ x,
                                              const float* __restrict__ Wd,
                                              const float* __restrict__ bd,
                                              float* __restrict__ nfeat) {
    __shared__ float lds[IN_CH * 65];   // 66.6KB
    for (int idx = threadIdx.x; idx < IN_CH * ADP; idx += 256) {
        int c = idx >> 8;
        int k = idx & 255;
        lds[k * 65 + c] = Wd[idx];
    }
    __syncthreads();
    int wv = threadIdx.x >> 6;
    int lane = threadIdx.x & 63;
    float b = bd[lane];
    for (int g = blockIdx.x * 4 + wv; g < N_NODES / 8; g += gridDim.x * 4) {
        int n0 = g * 8;
        const float4* r0 = (const float4*)(x + (size_t)(n0 + 0) * IN_CH);
        const float4* r1 = (const float4*)(x + (size_t)(n0 + 1) * IN_CH);
        const float4* r2 = (const float4*)(x + (size_t)(n0 + 2) * IN_CH);
        const float4* r3 = (const float4*)(x + (size_t)(n0 + 3) * IN_CH);
        const float4* r4 = (const float4*)(x + (size_t)(n0 + 4) * IN_CH);
        const float4* r5 = (const float4*)(x + (size_t)(n0 + 5) * IN_CH);
        const float4* r6 = (const float4*)(x + (size_t)(n0 + 6) * IN_CH);
        const float4* r7 = (const float4*)(x + (size_t)(n0 + 7) * IN_CH);
        float a0 = b, a1 = b, a2 = b, a3 = b, a4 = b, a5 = b, a6 = b, a7 = b;
        #pragma unroll 2
        for (int k4 = 0; k4 < IN_CH / 4; k4++) {
            float4 v0 = r0[k4], v1 = r1[k4], v2 = r2[k4], v3 = r3[k4];
            float4 v4 = r4[k4], v5 = r5[k4], v6 = r6[k4], v7 = r7[k4];
            const float* p0 = (const float*)&v0;
            const float* p1 = (const float*)&v1;
            const float* p2 = (const float*)&v2;
            const float* p3 = (const float*)&v3;
            const float* p4 = (const float*)&v4;
            const float* p5 = (const float*)&v5;
            const float* p6 = (const float*)&v6;
            const float* p7 = (const float*)&v7;
            #pragma unroll
            for (int j = 0; j < 4; j++) {
                float wt = lds[(4 * k4 + j) * 65 + lane];
                a0 += p0[j] * wt; a1 += p1[j] * wt; a2 += p2[j] * wt; a3 += p3[j] * wt;
                a4 += p4[j] * wt; a5 += p5[j] * wt; a6 += p6[j] * wt; a7 += p7[j] * wt;
            }
        }
        nfeat[(size_t)(n0 + 0) * ADP + lane] = fmaxf(a0, 0.f);
        nfeat[(size_t)(n0 + 1) * ADP + lane] = fmaxf(a1, 0.f);
        nfeat[(size_t)(n0 + 2) * ADP + lane] = fmaxf(a2, 0.f);
        nfeat[(size_t)(n0 + 3) * ADP + lane] = fmaxf(a3, 0.f);
        nfeat[(size_t)(n0 + 4) * ADP + lane] = fmaxf(a4, 0.f);
        nfeat[(size_t)(n0 + 5) * ADP + lane] = fmaxf(a5, 0.f);
        nfeat[(size_t)(n0 + 6) * ADP + lane] = fmaxf(a6, 0.f);
        nfeat[(size_t)(n0 + 7) * ADP + lane] = fmaxf(a7, 0.f);
    }
}

// ---------------- K5: fused = relu(W_fusion @ [nf | ntf] + b) ----------------
__global__ __launch_bounds__(256) void k_fuse(const float* __restrict__ nfeat,
                                              const float* __restrict__ ntf,
                                              const float* __restrict__ Wf,
                                              const float* __restrict__ bf,
                                              float* __restrict__ fused) {
    __shared__ float lds[2 * ADP * 65];  // 33.3KB
    for (int idx = threadIdx.x; idx < 2 * ADP * ADP; idx += 256) {
        int c = idx >> 7;
        int k = idx & 127;
        lds[k * 65 + c] = Wf[idx];
    }
    __syncthreads();
    int wv = threadIdx.x >> 6;
    int lane = threadIdx.x & 63;
    float b = bf[lane];
    for (int g = blockIdx.x * 4 + wv; g < N_NODES / 8; g += gridDim.x * 4) {
        int n0 = g * 8;
        float a0 = b, a1 = b, a2 = b, a3 = b, a4 = b, a5 = b, a6 = b, a7 = b;
        #pragma unroll
        for (int half = 0; half < 2; half++) {
            const float* srcbase = half ? ntf : nfeat;
            const float4* r0 = (const float4*)(srcbase + (size_t)(n0 + 0) * ADP);
            const float4* r1 = (const float4*)(srcbase + (size_t)(n0 + 1) * ADP);
            const float4* r2 = (const float4*)(srcbase + (size_t)(n0 + 2) * ADP);
            const float4* r3 = (const float4*)(srcbase + (size_t)(n0 + 3) * ADP);
            const float4* r4 = (const float4*)(srcbase + (size_t)(n0 + 4) * ADP);
            const float4* r5 = (const float4*)(srcbase + (size_t)(n0 + 5) * ADP);
            const float4* r6 = (const float4*)(srcbase + (size_t)(n0 + 6) * ADP);
            const float4* r7 = (const float4*)(srcbase + (size_t)(n0 + 7) * ADP);
            #pragma unroll 2
            for (int k4 = 0; k4 < ADP / 4; k4++) {
                float4 v0 = r0[k4], v1 = r1[k4], v2 = r2[k4], v3 = r3[k4];
                float4 v4 = r4[k4], v5 = r5[k4], v6 = r6[k4], v7 = r7[k4];
                const float* p0 = (const float*)&v0;
                const float* p1 = (const float*)&v1;
                const float* p2 = (const float*)&v2;
                const float* p3 = (const float*)&v3;
                const float* p4 = (const float*)&v4;
                const float* p5 = (const float*)&v5;
                const float* p6 = (const float*)&v6;
                const float* p7 = (const float*)&v7;
                #pragma unroll
                for (int j = 0; j < 4; j++) {
                    float wt = lds[(half * ADP + 4 * k4 + j) * 65 + lane];
                    a0 += p0[j] * wt; a1 += p1[j] * wt; a2 += p2[j] * wt; a3 += p3[j] * wt;
                    a4 += p4[j] * wt; a5 += p5[j] * wt; a6 += p6[j] * wt; a7 += p7[j] * wt;
                }
            }
        }
        fused[(size_t)(n0 + 0) * ADP + lane] = fmaxf(a0, 0.f);
        fused[(size_t)(n0 + 1) * ADP + lane] = fmaxf(a1, 0.f);
        fused[(size_t)(n0 + 2) * ADP + lane] = fmaxf(a2, 0.f);
        fused[(size_t)(n0 + 3) * ADP + lane] = fmaxf(a3, 0.f);
        fused[(size_t)(n0 + 4) * ADP + lane] = fmaxf(a4, 0.f);
        fused[(size_t)(n0 + 5) * ADP + lane] = fmaxf(a5, 0.f);
        fused[(size_t)(n0 + 6) * ADP + lane] = fmaxf(a6, 0.f);
        fused[(size_t)(n0 + 7) * ADP + lane] = fmaxf(a7, 0.f);
    }
}

// ---------------- K6: out = x + fused @ W_up^T + b_up ------------------------
__global__ __launch_bounds__(256) void k_up(const float* __restrict__ fused,
                                            const float* __restrict__ x,
                                            const float* __restrict__ Wu,
                                            const float* __restrict__ bu,
                                            float* __restrict__ out) {
    int t = threadIdx.x;
    float w[ADP];
    {
        const float4* w4 = (const float4*)(Wu + (size_t)t * ADP);
        #pragma unroll
        for (int k4 = 0; k4 < ADP / 4; k4++) {
            float4 v = w4[k4];
            w[4*k4+0] = v.x; w[4*k4+1] = v.y; w[4*k4+2] = v.z; w[4*k4+3] = v.w;
        }
    }
    float b = bu[t];
    for (int n = blockIdx.x * 2; n < N_NODES; n += gridDim.x * 2) {
        const float4* f0 = (const float4*)(fused + (size_t)n * ADP);
        const float4* f1 = (const float4*)(fused + (size_t)(n + 1) * ADP);
        float acc0 = b, acc1 = b;
        #pragma unroll
        for (int k4 = 0; k4 < ADP / 4; k4++) {
            float4 v0 = f0[k4], v1 = f1[k4];
            acc0 += v0.x*w[4*k4+0] + v0.y*w[4*k4+1] + v0.z*w[4*k4+2] + v0.w*w[4*k4+3];
            acc1 += v1.x*w[4*k4+0] + v1.y*w[4*k4+1] + v1.z*w[4*k4+2] + v1.w*w[4*k4+3];
        }
        size_t o0 = (size_t)n * IN_CH + t;
        size_t o1 = (size_t)(n + 1) * IN_CH + t;
        out[o0] = x[o0] + acc0;
        out[o1] = x[o1] + acc1;
    }
}

extern "C" void kernel_launch(void* const* d_in, const int* in_sizes, int n_in,
                              void* d_out, int out_size, void* d_ws, size_t ws_size,
                              hipStream_t stream) {
    const float* x   = (const float*)d_in[0];
    const int*   ei  = (const int*)d_in[1];     // [2, E]; row 0 = src
    const float* ea  = (const float*)d_in[2];
    const float* Wd  = (const float*)d_in[3];
    const float* bd  = (const float*)d_in[4];
    const float* Wt  = (const float*)d_in[5];
    const float* bt  = (const float*)d_in[6];
    const float* Wf  = (const float*)d_in[7];
    const float* bf  = (const float*)d_in[8];
    const float* Wu  = (const float*)d_in[9];
    const float* bu  = (const float*)d_in[10];
    float* out = (float*)d_out;

    int* deg    = (int*)d_ws;                       // [N]
    int* offs   = deg + N_NODES;                    // [N]
    int* gcnt   = offs + N_NODES;                   // [256]
    int* gbase  = gcnt + 256;                       // [256]
    int* elist  = gbase + 256;                      // [E]
    float* ntf   = (float*)(elist + N_EDGES);       // [N*64]
    float* nfeat = ntf + (size_t)N_NODES * ADP;     // [N*64]
    float* fused = nfeat + (size_t)N_NODES * ADP;   // [N*64]
    // gbuf (196*12288 ints = 9.63MB) aliases nfeat (12.8MB): dead before k_down
    int* gbuf = (int*)nfeat;

    (void)hipMemsetAsync(gcnt, 0, GRP * sizeof(int), stream);

    k_bucket    <<<  196, 256, 0, stream>>>(ei, gcnt, gbuf);
    k_bscan     <<<    1, 256, 0, stream>>>(gcnt, gbase);
    k_build     <<<  GRP, 256, 0, stream>>>(gcnt, gbase, gbuf, deg, offs, elist);
    k_gatherproj<<<12500, 256, 0, stream>>>(ea, offs, deg, elist, Wt, bt, ntf);
    k_down      <<<  512, 256, 0, stream>>>(x, Wd, bd, nfeat);
    k_fuse      <<< 1024, 256, 0, stream>>>(nfeat, ntf, Wf, bf, fused);
    k_up        <<< 4096, 256, 0, stream>>>(fused, x, Wu, bu, out);
}

// Round 3
// 478.990 us; speedup vs baseline: 1.6827x; 1.3742x over previous
//
#include <hip/hip_runtime.h>

#define N_NODES 50000
#define N_EDGES 1600000
#define IN_CH   256
#define ADP     64
#define EDGE_DIM 32
#define GRP     196     // ceil(50000/256) node groups
#define GCAP    12288   // per-group bucket capacity (mean 8192, sd ~90)
#define EPB_A   2048    // edges per block in k_bucket
#define NB_BUCKET ((N_EDGES + EPB_A - 1) / EPB_A)   // 782
#define NT16    (N_NODES / 16)                      // 3125 node tiles
#define NB_GEMM ((NT16 + 3) / 4)                    // 782

typedef __fp16 h2 __attribute__((ext_vector_type(2)));
typedef _Float16 f16x8 __attribute__((ext_vector_type(8)));
typedef float f32x4 __attribute__((ext_vector_type(4)));
union F8 { f16x8 v; h2 h[4]; };

__device__ inline f16x8 cvt8(float4 a, float4 b) {
    F8 r;
    r.h[0] = __builtin_amdgcn_cvt_pkrtz(a.x, a.y);
    r.h[1] = __builtin_amdgcn_cvt_pkrtz(a.z, a.w);
    r.h[2] = __builtin_amdgcn_cvt_pkrtz(b.x, b.y);
    r.h[3] = __builtin_amdgcn_cvt_pkrtz(b.z, b.w);
    return r.v;
}

// ---------------- K_A: coarse bucket by 256-node group -----------------------
__global__ __launch_bounds__(256) void k_bucket(const int* __restrict__ ei_src,
                                                int* __restrict__ gcnt,
                                                int* __restrict__ gbuf) {
    __shared__ int cnt[GRP];
    __shared__ int cur[GRP];
    int t = threadIdx.x;
    if (t < GRP) cnt[t] = 0;
    __syncthreads();
    int base = blockIdx.x * EPB_A;
    int s[8];
    #pragma unroll
    for (int k = 0; k < 8; k++) {
        int e = base + k * 256 + t;
        int v = (e < N_EDGES) ? ei_src[e] : -1;
        s[k] = v;
        if (v >= 0) atomicAdd(&cnt[v >> 8], 1);
    }
    __syncthreads();
    if (t < GRP) cur[t] = atomicAdd(&gcnt[t], cnt[t]);
    __syncthreads();
    #pragma unroll
    for (int k = 0; k < 8; k++) {
        int v = s[k];
        if (v >= 0) {
            int e = base + k * 256 + t;
            int g = v >> 8;
            int slot = atomicAdd(&cur[g], 1);
            if (slot < GCAP)
                gbuf[g * GCAP + slot] = (e << 8) | (v & 255);
        }
    }
}

// ---------------- K_B: per-group deg/offs/elist build (inline global scan) ---
__global__ __launch_bounds__(512) void k_build(const int* __restrict__ gcnt,
                                               const int* __restrict__ gbuf,
                                               int* __restrict__ deg,
                                               int* __restrict__ offs,
                                               int* __restrict__ elist) {
    __shared__ int a[256], b[256], dcnt[256], cur[256];
    int t = threadIdx.x;
    int g = blockIdx.x;
    // every block scans the 196 capped group counts -> its global base
    if (t < 256) a[t] = (t < GRP) ? min(gcnt[t], GCAP) : 0;
    __syncthreads();
    int* sp = a; int* dp = b;
    for (int o = 1; o < 256; o <<= 1) {
        if (t < 256) { int v2 = sp[t]; if (t >= o) v2 += sp[t - o]; dp[t] = v2; }
        __syncthreads();
        int* tmp = sp; sp = dp; dp = tmp;
    }
    int base = (g == 0) ? 0 : sp[g - 1];
    int sz = min(gcnt[g], GCAP);
    if (t < 256) dcnt[t] = 0;
    __syncthreads();
    const int* src = gbuf + (size_t)g * GCAP;
    for (int i = t; i < sz; i += 512) atomicAdd(&dcnt[src[i] & 255], 1);
    __syncthreads();
    if (t < 256) a[t] = dcnt[t];
    __syncthreads();
    sp = a; dp = b;
    for (int o = 1; o < 256; o <<= 1) {
        if (t < 256) { int v2 = sp[t]; if (t >= o) v2 += sp[t - o]; dp[t] = v2; }
        __syncthreads();
        int* tmp = sp; sp = dp; dp = tmp;
    }
    if (t < 256) {
        int v = dcnt[t];
        int pref = sp[t] - v;
        int n = g * 256 + t;
        if (n < N_NODES) { deg[n] = v; offs[n] = base + pref; }
        cur[t] = pref;
    }
    __syncthreads();
    for (int i = t; i < sz; i += 512) {
        int p = src[i];
        int slot = atomicAdd(&cur[p & 255], 1);
        elist[base + slot] = p >> 8;
    }
}

// ---------------- K3: gather + time-proj via MFMA + mean ---------------------
// One wave per node. 16-edge chunks: lane gathers 16B (8 dims) of edge
// (chunk+col) -> A-frag; 4 MFMA (N=64) per chunk; relu+bias, row-sum in
// regs, cross-quadrant shfl reduce at the end. No LDS.
__global__ __launch_bounds__(256) void k_gatherproj(const float* __restrict__ ea,
                                                    const int* __restrict__ offs,
                                                    const int* __restrict__ deg,
                                                    const int* __restrict__ elist,
                                                    const float* __restrict__ Wt,
                                                    const float* __restrict__ bt,
                                                    float* __restrict__ ntf) {
    int t = threadIdx.x;
    int lane = t & 63;
    int col = lane & 15, q = lane >> 4;
    f16x8 bf[4];
    float bias[4];
    #pragma unroll
    for (int nt = 0; nt < 4; nt++) {
        const float4* wr = (const float4*)(Wt + (size_t)(nt * 16 + col) * EDGE_DIM + q * 8);
        bf[nt] = cvt8(wr[0], wr[1]);
        bias[nt] = bt[nt * 16 + col];
    }
    int n = blockIdx.x * 4 + (t >> 6);
    if (n >= N_NODES) return;
    int st = offs[n], d = deg[n];
    const float4* ea4 = (const float4*)ea;
    float s0 = 0.f, s1 = 0.f, s2 = 0.f, s3 = 0.f;
    f32x4 z = {0.f, 0.f, 0.f, 0.f};
    int base = 0;
    // 32-edge main steps: two independent chunks in flight
    for (; base + 32 <= d; base += 32) {
        int e0 = elist[st + base + col];
        int e1 = elist[st + base + 16 + col];
        const float4* p0 = ea4 + (size_t)e0 * 8 + q * 2;
        const float4* p1 = ea4 + (size_t)e1 * 8 + q * 2;
        float4 va0 = p0[0], va1 = p0[1];
        float4 vb0 = p1[0], vb1 = p1[1];
        f16x8 afA = cvt8(va0, va1);
        f16x8 afB = cvt8(vb0, vb1);
        f32x4 dA0 = __builtin_amdgcn_mfma_f32_16x16x32_f16(afA, bf[0], z, 0, 0, 0);
        f32x4 dA1 = __builtin_amdgcn_mfma_f32_16x16x32_f16(afA, bf[1], z, 0, 0, 0);
        f32x4 dA2 = __builtin_amdgcn_mfma_f32_16x16x32_f16(afA, bf[2], z, 0, 0, 0);
        f32x4 dA3 = __builtin_amdgcn_mfma_f32_16x16x32_f16(afA, bf[3], z, 0, 0, 0);
        f32x4 dB0 = __builtin_amdgcn_mfma_f32_16x16x32_f16(afB, bf[0], z, 0, 0, 0);
        f32x4 dB1 = __builtin_amdgcn_mfma_f32_16x16x32_f16(afB, bf[1], z, 0, 0, 0);
        f32x4 dB2 = __builtin_amdgcn_mfma_f32_16x16x32_f16(afB, bf[2], z, 0, 0, 0);
        f32x4 dB3 = __builtin_amdgcn_mfma_f32_16x16x32_f16(afB, bf[3], z, 0, 0, 0);
        #pragma unroll
        for (int r = 0; r < 4; r++) {
            s0 += fmaxf(dA0[r] + bias[0], 0.f) + fmaxf(dB0[r] + bias[0], 0.f);
            s1 += fmaxf(dA1[r] + bias[1], 0.f) + fmaxf(dB1[r] + bias[1], 0.f);
            s2 += fmaxf(dA2[r] + bias[2], 0.f) + fmaxf(dB2[r] + bias[2], 0.f);
            s3 += fmaxf(dA3[r] + bias[3], 0.f) + fmaxf(dB3[r] + bias[3], 0.f);
        }
    }
    // tail: 16-edge chunks with row mask
    for (; base < d; base += 16) {
        int cnt = d - base; if (cnt > 16) cnt = 16;
        int e = elist[st + base + (col < cnt ? col : cnt - 1)];
        const float4* p = ea4 + (size_t)e * 8 + q * 2;
        float4 v0 = p[0], v1 = p[1];
        f16x8 af = cvt8(v0, v1);
        f32x4 d0 = __builtin_amdgcn_mfma_f32_16x16x32_f16(af, bf[0], z, 0, 0, 0);
        f32x4 d1 = __builtin_amdgcn_mfma_f32_16x16x32_f16(af, bf[1], z, 0, 0, 0);
        f32x4 d2 = __builtin_amdgcn_mfma_f32_16x16x32_f16(af, bf[2], z, 0, 0, 0);
        f32x4 d3 = __builtin_amdgcn_mfma_f32_16x16x32_f16(af, bf[3], z, 0, 0, 0);
        #pragma unroll
        for (int r = 0; r < 4; r++) {
            bool ok = (q * 4 + r) < cnt;
            s0 += ok ? fmaxf(d0[r] + bias[0], 0.f) : 0.f;
            s1 += ok ? fmaxf(d1[r] + bias[1], 0.f) : 0.f;
            s2 += ok ? fmaxf(d2[r] + bias[2], 0.f) : 0.f;
            s3 += ok ? fmaxf(d3[r] + bias[3], 0.f) : 0.f;
        }
    }
    s0 += __shfl_xor(s0, 16, 64); s0 += __shfl_xor(s0, 32, 64);
    s1 += __shfl_xor(s1, 16, 64); s1 += __shfl_xor(s1, 32, 64);
    s2 += __shfl_xor(s2, 16, 64); s2 += __shfl_xor(s2, 32, 64);
    s3 += __shfl_xor(s3, 16, 64); s3 += __shfl_xor(s3, 32, 64);
    float res = (q == 0) ? s0 : (q == 1) ? s1 : (q == 2) ? s2 : s3;
    ntf[(size_t)n * ADP + lane] = res / fmaxf((float)d, 1.f);
}

// ---------------- K4: node_feat = relu(x @ W_down^T + b) via MFMA ------------
// Wave = 16-node tile. Wd staged fragment-ordered in LDS (contiguous 16B per
// lane -> optimal ds_read_b128). A-loads lane-distributed (coalesced-ish).
__global__ __launch_bounds__(256) void k_down(const float* __restrict__ x,
                                              const float* __restrict__ Wd,
                                              const float* __restrict__ bd,
                                              float* __restrict__ nfeat) {
    __shared__ f16x8 wlds[8][4][64];   // [kc][nt][lane] = 32KB
    int t = threadIdx.x;
    int lane = t & 63, col = lane & 15, q = lane >> 4;
    for (int f = t; f < 8 * 4 * 64; f += 256) {
        int l = f & 63, ntk = f >> 6;
        int nt = ntk & 3, kc = ntk >> 2;
        const float4* wr = (const float4*)(Wd + (size_t)(nt * 16 + (l & 15)) * IN_CH
                                           + kc * 32 + (l >> 4) * 8);
        wlds[kc][nt][l] = cvt8(wr[0], wr[1]);
    }
    __syncthreads();
    int tile = blockIdx.x * 4 + (t >> 6);
    if (tile >= NT16) return;
    int n0 = tile * 16;
    float bias[4];
    #pragma unroll
    for (int nt = 0; nt < 4; nt++) bias[nt] = bd[nt * 16 + col];
    f32x4 z = {0.f, 0.f, 0.f, 0.f};
    f32x4 acc[4];
    #pragma unroll
    for (int nt = 0; nt < 4; nt++) acc[nt] = z;
    #pragma unroll
    for (int kc = 0; kc < 8; kc++) {
        const float4* xr = (const float4*)(x + (size_t)(n0 + col) * IN_CH + kc * 32 + q * 8);
        float4 v0 = xr[0], v1 = xr[1];
        f16x8 af = cvt8(v0, v1);
        #pragma unroll
        for (int nt = 0; nt < 4; nt++)
            acc[nt] = __builtin_amdgcn_mfma_f32_16x16x32_f16(af, wlds[kc][nt][lane], acc[nt], 0, 0, 0);
    }
    #pragma unroll
    for (int nt = 0; nt < 4; nt++)
        #pragma unroll
        for (int r = 0; r < 4; r++)
            nfeat[(size_t)(n0 + q * 4 + r) * ADP + nt * 16 + col] = fmaxf(acc[nt][r] + bias[nt], 0.f);
}

// ---------------- K5: fused = relu([nf|ntf] @ Wf^T + b) via MFMA -------------
__global__ __launch_bounds__(256) void k_fuse(const float* __restrict__ nfeat,
                                              const float* __restrict__ ntf,
                                              const float* __restrict__ Wf,
                                              const float* __restrict__ bf_,
                                              float* __restrict__ fused) {
    __shared__ f16x8 wlds[4][4][64];   // 16KB
    int t = threadIdx.x;
    int lane = t & 63, col = lane & 15, q = lane >> 4;
    for (int f = t; f < 4 * 4 * 64; f += 256) {
        int l = f & 63, ntk = f >> 6;
        int nt = ntk & 3, kc = ntk >> 2;
        const float4* wr = (const float4*)(Wf + (size_t)(nt * 16 + (l & 15)) * (2 * ADP)
                                           + kc * 32 + (l >> 4) * 8);
        wlds[kc][nt][l] = cvt8(wr[0], wr[1]);
    }
    __syncthreads();
    int tile = blockIdx.x * 4 + (t >> 6);
    if (tile >= NT16) return;
    int n0 = tile * 16;
    float bias[4];
    #pragma unroll
    for (int nt = 0; nt < 4; nt++) bias[nt] = bf_[nt * 16 + col];
    f32x4 z = {0.f, 0.f, 0.f, 0.f};
    f32x4 acc[4];
    #pragma unroll
    for (int nt = 0; nt < 4; nt++) acc[nt] = z;
    #pragma unroll
    for (int kc = 0; kc < 4; kc++) {
        const float* srcb = (kc < 2) ? nfeat : ntf;
        int ko = (kc & 1) * 32;
        const float4* xr = (const float4*)(srcb + (size_t)(n0 + col) * ADP + ko + q * 8);
        float4 v0 = xr[0], v1 = xr[1];
        f16x8 af = cvt8(v0, v1);
        #pragma unroll
        for (int nt = 0; nt < 4; nt++)
            acc[nt] = __builtin_amdgcn_mfma_f32_16x16x32_f16(af, wlds[kc][nt][lane], acc[nt], 0, 0, 0);
    }
    #pragma unroll
    for (int nt = 0; nt < 4; nt++)
        #pragma unroll
        for (int r = 0; r < 4; r++)
            fused[(size_t)(n0 + q * 4 + r) * ADP + nt * 16 + col] = fmaxf(acc[nt][r] + bias[nt], 0.f);
}

// ---------------- K6: out = x + fused @ Wu^T + bu via MFMA -------------------
__global__ __launch_bounds__(256) void k_up(const float* __restrict__ fused,
                                            const float* __restrict__ x,
                                            const float* __restrict__ Wu,
                                            const float* __restrict__ bu,
                                            float* __restrict__ out) {
    __shared__ f16x8 wlds[2][16][64];   // 32KB
    int t = threadIdx.x;
    int lane = t & 63, col = lane & 15, q = lane >> 4;
    for (int f = t; f < 2 * 16 * 64; f += 256) {
        int l = f & 63, ntk = f >> 6;
        int nt = ntk & 15, kc = ntk >> 4;
        const float4* wr = (const float4*)(Wu + (size_t)(nt * 16 + (l & 15)) * ADP
                                           + kc * 32 + (l >> 4) * 8);
        wlds[kc][nt][l] = cvt8(wr[0], wr[1]);
    }
    __syncthreads();
    int tile = blockIdx.x * 4 + (t >> 6);
    if (tile >= NT16) return;
    int n0 = tile * 16;
    f32x4 z = {0.f, 0.f, 0.f, 0.f};
    f32x4 acc[16];
    #pragma unroll
    for (int nt = 0; nt < 16; nt++) acc[nt] = z;
    #pragma unroll
    for (int kc = 0; kc < 2; kc++) {
        const float4* xr = (const float4*)(fused + (size_t)(n0 + col) * ADP + kc * 32 + q * 8);
        float4 v0 = xr[0], v1 = xr[1];
        f16x8 af = cvt8(v0, v1);
        #pragma unroll
        for (int nt = 0; nt < 16; nt++)
            acc[nt] = __builtin_amdgcn_mfma_f32_16x16x32_f16(af, wlds[kc][nt][lane], acc[nt], 0, 0, 0);
    }
    #pragma unroll
    for (int nt = 0; nt < 16; nt++) {
        float b = bu[nt * 16 + col];
        #pragma unroll
        for (int r = 0; r < 4; r++) {
            size_t idx = (size_t)(n0 + q * 4 + r) * IN_CH + nt * 16 + col;
            out[idx] = x[idx] + acc[nt][r] + b;
        }
    }
}

extern "C" void kernel_launch(void* const* d_in, const int* in_sizes, int n_in,
                              void* d_out, int out_size, void* d_ws, size_t ws_size,
                              hipStream_t stream) {
    const float* x   = (const float*)d_in[0];
    const int*   ei  = (const int*)d_in[1];     // [2, E]; row 0 = src
    const float* ea  = (const float*)d_in[2];
    const float* Wd  = (const float*)d_in[3];
    const float* bd  = (const float*)d_in[4];
    const float* Wt  = (const float*)d_in[5];
    const float* bt  = (const float*)d_in[6];
    const float* Wf  = (const float*)d_in[7];
    const float* bf  = (const float*)d_in[8];
    const float* Wu  = (const float*)d_in[9];
    const float* bu  = (const float*)d_in[10];
    float* out = (float*)d_out;

    int* deg    = (int*)d_ws;                       // [N]
    int* offs   = deg + N_NODES;                    // [N]
    int* gcnt   = offs + N_NODES;                   // [256]
    int* elist  = gcnt + 256;                       // [E]
    float* ntf   = (float*)(elist + N_EDGES);       // [N*64]
    float* nfeat = ntf + (size_t)N_NODES * ADP;     // [N*64]
    float* fused = nfeat + (size_t)N_NODES * ADP;   // [N*64]
    // gbuf (196*12288 ints = 9.63MB) aliases nfeat (12.8MB): dead before k_down
    int* gbuf = (int*)nfeat;

    (void)hipMemsetAsync(gcnt, 0, 256 * sizeof(int), stream);

    k_bucket    <<<NB_BUCKET, 256, 0, stream>>>(ei, gcnt, gbuf);
    k_build     <<<     GRP, 512, 0, stream>>>(gcnt, gbuf, deg, offs, elist);
    k_gatherproj<<<   12500, 256, 0, stream>>>(ea, offs, deg, elist, Wt, bt, ntf);
    k_down      <<< NB_GEMM, 256, 0, stream>>>(x, Wd, bd, nfeat);
    k_fuse      <<< NB_GEMM, 256, 0, stream>>>(nfeat, ntf, Wf, bf, fused);
    k_up        <<< NB_GEMM, 256, 0, stream>>>(fused, x, Wu, bu, out);
}